// Round 10
// baseline (397.948 us; speedup 1.0000x reference)
//
#include <hip/hip_runtime.h>
#include <hip/hip_bf16.h>
#include <math.h>

#define L4K 4096
#define NCH 32     // scan chunks over L
#define CL  128    // timesteps per chunk
#define SPN (128*4096)   // floats per n in S planes

typedef __attribute__((ext_vector_type(8))) short short8;
typedef __attribute__((ext_vector_type(4))) float f32x4;

__device__ __forceinline__ unsigned short f2b(float f) {
    unsigned int u = __float_as_uint(f);
    unsigned int r = u + 0x7FFFu + ((u >> 16) & 1u);
    return (unsigned short)(r >> 16);
}
__device__ __forceinline__ float b2f(unsigned short h) {
    return __uint_as_float(((unsigned int)h) << 16);
}
// sum over each 16-lane row via fused v_add_f32_dpp (bound_ctrl=true enables combine)
__device__ __forceinline__ float rowsum16(float p) {
    int t;
    t = __builtin_amdgcn_update_dpp(0, __float_as_int(p), 0x128, 0xf, 0xf, true);
    p += __int_as_float(t);
    t = __builtin_amdgcn_update_dpp(0, __float_as_int(p), 0x124, 0xf, 0xf, true);
    p += __int_as_float(t);
    t = __builtin_amdgcn_update_dpp(0, __float_as_int(p), 0x122, 0xf, 0xf, true);
    p += __int_as_float(t);
    t = __builtin_amdgcn_update_dpp(0, __float_as_int(p), 0x121, 0xf, 0xf, true);
    p += __int_as_float(t);
    return p;
}

// ---------------- K1: pre-LN + bott_in + in_proj (plane outputs) ----------------
__global__ __launch_bounds__(256) void k1_pre(
    const float* __restrict__ x, const float* __restrict__ png, const float* __restrict__ pnb,
    const float* __restrict__ biw, const float* __restrict__ bib, const float* __restrict__ ipw,
    float* __restrict__ zc, float* __restrict__ xcp, float* __restrict__ zg)
{
    __shared__ float xs[128*32];
    __shared__ float wl[64*128];
    __shared__ float zs[32*65];
    __shared__ float ipl[64*16];
    __shared__ float pngs[128], pnbs[128];
    int tid = threadIdx.x;
    int l0 = blockIdx.x*32, b = blockIdx.y;
    const float* xb = x + (size_t)b*128*L4K;
    for (int it = 0; it < 16; ++it) {
        int f = it*256 + tid; int c = f>>5, i = f&31;
        xs[f] = xb[(size_t)c*L4K + l0 + i];
    }
    for (int f = tid; f < 8192; f += 256) wl[f] = biw[f];
    for (int f = tid; f < 1024; f += 256) ipl[f] = ipw[f];
    if (tid < 128) { pngs[tid] = png[tid]; pnbs[tid] = pnb[tid]; }
    __syncthreads();
    int i = tid & 31, q = tid >> 5;
    float s = 0.f, s2 = 0.f;
    for (int c = 0; c < 128; ++c) { float v = xs[c*32+i]; s += v; s2 = fmaf(v,v,s2); }
    float mn = s*(1.f/128.f);
    float rstd = rsqrtf(s2*(1.f/128.f) - mn*mn + 1e-5f);
    float z[8];
    #pragma unroll
    for (int jj = 0; jj < 8; ++jj) z[jj] = bib[q*8+jj];
    for (int c = 0; c < 128; ++c) {
        float xv = (xs[c*32+i] - mn)*rstd*pngs[c] + pnbs[c];
        #pragma unroll
        for (int jj = 0; jj < 8; ++jj) z[jj] = fmaf(xv, wl[(q*8+jj)*128 + c], z[jj]);
    }
    #pragma unroll
    for (int jj = 0; jj < 8; ++jj) zs[i*65 + q*8 + jj] = z[jj];
    __syncthreads();
    if (tid < 128) {
        int i2 = tid & 31, g = tid >> 5;
        int n = g*8 + b; int l = l0 + i2;
        float zv[16];
        #pragma unroll
        for (int k = 0; k < 16; ++k) zv[k] = zs[i2*65 + g*16 + k];
        float* zcb = zc + ((size_t)n*16)*L4K + l;
        #pragma unroll
        for (int k = 0; k < 16; ++k) zcb[(size_t)k*L4K] = zv[k];
        float* xo = xcp + ((size_t)n*32)*L4K + l;
        float* zo = zg  + ((size_t)n*32)*L4K + l;
        #pragma unroll
        for (int o = 0; o < 64; ++o) {
            float a = 0.f;
            #pragma unroll
            for (int k = 0; k < 16; ++k) a = fmaf(zv[k], ipl[o*16+k], a);
            if (o < 32) xo[(size_t)o*L4K] = a; else zo[(size_t)(o-32)*L4K] = a;
        }
    }
}

// ---------------- K2: conv + silu + x_proj + dt -> S planes (split halves) ----
// S planes per n (stride SPN): [0:32)=dt, [32:64)=dx, [64:80)=B, [80:96)=C, [96:128)=xc
__global__ __launch_bounds__(256) void k2_conv(
    const float* __restrict__ xcp, const float* __restrict__ cw, const float* __restrict__ cb,
    const float* __restrict__ xpw, const float* __restrict__ dtw, const float* __restrict__ dtb,
    float* __restrict__ S)
{
    __shared__ float xt[32*132];    // [d][r], r = 0..130
    __shared__ float xcs[128*33];   // [t][d]
    __shared__ float Bs[16*128];    // [o][t]
    __shared__ float dtrs[128];
    __shared__ float cwl[128], cbl[32], xpl[33*32], dtwl[32], dtbl[32];
    int tid = threadIdx.x;
    int tl = tid & 127, p = tid >> 7;
    int t0 = blockIdx.x*128; int n = blockIdx.y;
    const float* xb = xcp + (size_t)n*32*L4K;
    #pragma unroll
    for (int dd = 0; dd < 16; ++dd) {
        int d = p*16 + dd;
        int t = t0 - 3 + tl;
        xt[d*132 + tl] = (t >= 0) ? xb[(size_t)d*L4K + t] : 0.f;
        if (tl < 3) xt[d*132 + 128 + tl] = xb[(size_t)d*L4K + t0 + 125 + tl];
    }
    if (tid < 128) cwl[tid] = cw[tid];
    else if (tid < 160) cbl[tid-128] = cb[tid-128];
    else if (tid < 192) dtwl[tid-160] = dtw[tid-160];
    else if (tid < 224) dtbl[tid-192] = dtb[tid-192];
    for (int f = tid; f < 33*32; f += 256) xpl[f] = xpw[f];
    __syncthreads();
    #pragma unroll
    for (int dd = 0; dd < 16; ++dd) {
        int d = p*16 + dd;
        float sv = cbl[d];
        #pragma unroll
        for (int k = 0; k < 4; ++k) sv = fmaf(cwl[d*4+k], xt[d*132 + tl + k], sv);
        xcs[tl*33 + d] = sv / (1.f + __expf(-sv));
    }
    __syncthreads();
    float* Sn = S + (size_t)n*SPN + t0 + tl;
    if (p == 0) {
        float dtr = 0.f;
        #pragma unroll
        for (int dd = 0; dd < 32; ++dd) dtr = fmaf(xcs[tl*33+dd], xpl[dd], dtr);
        dtrs[tl] = dtr;
        #pragma unroll
        for (int o = 0; o < 16; ++o) {
            float a = 0.f;
            #pragma unroll
            for (int dd = 0; dd < 32; ++dd) a = fmaf(xcs[tl*33+dd], xpl[(1+o)*32+dd], a);
            Bs[o*128 + tl] = a;
        }
    } else {
        #pragma unroll
        for (int o = 0; o < 16; ++o) {
            float a2 = 0.f;
            #pragma unroll
            for (int dd = 0; dd < 32; ++dd) a2 = fmaf(xcs[tl*33+dd], xpl[(17+o)*32+dd], a2);
            Sn[(size_t)(80+o)*L4K] = a2;
        }
    }
    __syncthreads();
    float dtr = dtrs[tl];
    #pragma unroll
    for (int dd = 0; dd < 16; ++dd) {
        int d = p*16 + dd;
        float xc = xcs[tl*33 + d];
        float dv = fmaf(dtr, dtwl[d], dtbl[d]);
        float sp = fmaxf(dv, 0.f) + log1pf(__expf(-fabsf(dv)));
        Sn[(size_t)d*L4K]      = sp;
        Sn[(size_t)(32+d)*L4K] = sp * xc;
        Sn[(size_t)(96+d)*L4K] = xc;
    }
    if (p == 1) {
        #pragma unroll
        for (int o = 0; o < 16; ++o) Sn[(size_t)(64+o)*L4K] = Bs[o*128 + tl];
    }
}

// ---------------- K3a: chunk-local scan (LDS pair-staged) ----------------
__global__ __launch_bounds__(512) void k3a_local(
    const float* __restrict__ S, const float* __restrict__ alog,
    float* __restrict__ chunkA, float* __restrict__ chunkH)
{
    __shared__ float2 pDT[32*130];   // (dt,dx)[d][t], stride 130
    __shared__ float  pB[16*132];    // B[s][t], stride 132
    int tid = threadIdx.x;
    int d = tid >> 4, s = tid & 15;
    int chunk = blockIdx.x, n = blockIdx.y;
    float A = -__expf(alog[d*16 + s]);
    const float* base = S + (size_t)n*SPN + (size_t)chunk*CL;
    {   // stage (dt,dx) pairs: thread = (sd, j), 8 t each
        int sd = tid >> 4, j = tid & 15;
        const float* dtp = base + (size_t)sd*L4K + j*8;
        const float* dxp = base + (size_t)(32+sd)*L4K + j*8;
        float4 a0 = *(const float4*)(dtp);
        float4 a1 = *(const float4*)(dtp+4);
        float4 b0 = *(const float4*)(dxp);
        float4 b1 = *(const float4*)(dxp+4);
        float2* w = pDT + sd*130 + j*8;
        *(float4*)(w+0) = make_float4(a0.x,b0.x,a0.y,b0.y);
        *(float4*)(w+2) = make_float4(a0.z,b0.z,a0.w,b0.w);
        *(float4*)(w+4) = make_float4(a1.x,b1.x,a1.y,b1.y);
        *(float4*)(w+6) = make_float4(a1.z,b1.z,a1.w,b1.w);
    }
    if (tid < 256) {   // stage B singles: thread = (ss, j), 8 t each
        int ss = tid >> 4, j = tid & 15;
        const float* bp = base + (size_t)(64+ss)*L4K + j*8;
        float4 v0 = *(const float4*)(bp);
        float4 v1 = *(const float4*)(bp+4);
        float* w = pB + ss*132 + j*8;
        *(float4*)(w+0) = v0;
        *(float4*)(w+4) = v1;
    }
    __syncthreads();
    float h = 0.f, ap = 1.f;
    #pragma unroll 4
    for (int t = 0; t < CL; ++t) {
        float2 dd = pDT[d*130 + t];
        float Bv = pB[s*132 + t];
        float dA = __expf(dd.x * A);
        h = fmaf(dA, h, dd.y * Bv);
        ap *= dA;
    }
    size_t idx = (size_t)chunk*16384 + n*512 + tid;
    chunkA[idx] = ap;
    chunkH[idx] = h;
}

// ---------------- K3b: prefix across chunks ----------------
__global__ __launch_bounds__(256) void k3b_prefix(
    const float* __restrict__ chunkA, const float* __restrict__ chunkH,
    float* __restrict__ hstart)
{
    int nds = blockIdx.x*256 + threadIdx.x;
    float h = 0.f;
    hstart[nds] = 0.f;
    for (int c = 0; c < NCH-1; ++c) {
        h = fmaf(h, chunkA[(size_t)c*16384 + nds], chunkH[(size_t)c*16384 + nds]);
        hstart[(size_t)(c+1)*16384 + nds] = h;
    }
}

// ---------------- K3c: recompute with start state, emit y planes ------------
__global__ __launch_bounds__(512) void k3c_emit(
    const float* __restrict__ S, const float* __restrict__ alog,
    const float* __restrict__ hstart, float* __restrict__ y)
{
    __shared__ float2 pDT[32*130];   // (dt,dx)[d][t]
    __shared__ float2 pBC[16*130];   // (B,C)[s][t]
    int tid = threadIdx.x;
    int d = tid >> 4, s = tid & 15;
    int chunk = blockIdx.x, n = blockIdx.y;
    float A = -__expf(alog[d*16 + s]);
    const float* base = S + (size_t)n*SPN + (size_t)chunk*CL;
    float h = hstart[(size_t)chunk*16384 + n*512 + tid];
    {   // stage (dt,dx)
        int sd = tid >> 4, j = tid & 15;
        const float* dtp = base + (size_t)sd*L4K + j*8;
        const float* dxp = base + (size_t)(32+sd)*L4K + j*8;
        float4 a0 = *(const float4*)(dtp);
        float4 a1 = *(const float4*)(dtp+4);
        float4 b0 = *(const float4*)(dxp);
        float4 b1 = *(const float4*)(dxp+4);
        float2* w = pDT + sd*130 + j*8;
        *(float4*)(w+0) = make_float4(a0.x,b0.x,a0.y,b0.y);
        *(float4*)(w+2) = make_float4(a0.z,b0.z,a0.w,b0.w);
        *(float4*)(w+4) = make_float4(a1.x,b1.x,a1.y,b1.y);
        *(float4*)(w+6) = make_float4(a1.z,b1.z,a1.w,b1.w);
    }
    if (tid < 256) {   // stage (B,C)
        int ss = tid >> 4, j = tid & 15;
        const float* bp = base + (size_t)(64+ss)*L4K + j*8;
        const float* cp = base + (size_t)(80+ss)*L4K + j*8;
        float4 v0 = *(const float4*)(bp);
        float4 v1 = *(const float4*)(bp+4);
        float4 c0 = *(const float4*)(cp);
        float4 c1 = *(const float4*)(cp+4);
        float2* w = pBC + ss*130 + j*8;
        *(float4*)(w+0) = make_float4(v0.x,c0.x,v0.y,c0.y);
        *(float4*)(w+2) = make_float4(v0.z,c0.z,v0.w,c0.w);
        *(float4*)(w+4) = make_float4(v1.x,c1.x,v1.y,c1.y);
        *(float4*)(w+6) = make_float4(v1.z,c1.z,v1.w,c1.w);
    }
    __syncthreads();
    float4* yb = (float4*)(y + ((size_t)n*32 + d)*L4K + (size_t)chunk*CL);
    for (int i = 0; i < CL/4; ++i) {
        float4 yv;
        #pragma unroll
        for (int u = 0; u < 4; ++u) {
            int t = i*4 + u;
            float2 dd = pDT[d*130 + t];
            float2 bc = pBC[s*130 + t];
            float dA = __expf(dd.x * A);
            h = fmaf(dA, h, dd.y * bc.x);
            ((float*)&yv)[u] = rowsum16(h * bc.y);
        }
        if (s == 0) yb[i] = yv;
    }
}

// ---------------- K5: gate + out_proj + residual -> m planes (split halves) --
__global__ __launch_bounds__(256) void k5_out(
    const float* __restrict__ y, const float* __restrict__ S, const float* __restrict__ zg,
    const float* __restrict__ zc, const float* __restrict__ Dp, const float* __restrict__ opw,
    float* __restrict__ m)
{
    __shared__ float vs[128*33];
    int tid = threadIdx.x;
    int tl = tid & 127, p = tid >> 7;
    int id = blockIdx.x*128 + tl;     // (n,t) pair
    int n = id >> 12, t = id & 4095;
    const float* yb  = y  + (size_t)n*32*L4K + t;
    const float* xcb = S  + (size_t)n*SPN + (size_t)96*L4K + t;
    const float* zgb = zg + (size_t)n*32*L4K + t;
    const float* zcb = zc + (size_t)n*16*L4K + t;
    #pragma unroll
    for (int dd2 = 0; dd2 < 16; ++dd2) {
        int dd = p*16 + dd2;
        float g = zgb[(size_t)dd*L4K];
        float sig = 1.f/(1.f + __expf(-g));
        vs[tl*33 + dd] = (yb[(size_t)dd*L4K] + xcb[(size_t)dd*L4K]*Dp[dd]) * (g*sig);
    }
    __syncthreads();
    int b = n & 7, g4 = n >> 3;
    float* mp = m + ((size_t)b*64 + g4*16)*L4K + t;
    #pragma unroll
    for (int jj = 0; jj < 8; ++jj) {
        int j = p*8 + jj;
        float a = zcb[(size_t)j*L4K];
        #pragma unroll
        for (int dd = 0; dd < 32; ++dd) a = fmaf(vs[tl*33+dd], opw[j*32+dd], a);
        mp[(size_t)j*L4K] = a;
    }
}

// ---------------- K6: post-LN + bott_out; outp fp32 [c][l] + bf16 [l][c] ----
__global__ __launch_bounds__(256) void k6_post(
    const float* __restrict__ m, const float* __restrict__ x,
    const float* __restrict__ pog, const float* __restrict__ pob,
    const float* __restrict__ bow, const float* __restrict__ bob,
    const float* __restrict__ rsp, float* __restrict__ outp,
    unsigned short* __restrict__ outpb)
{
    __shared__ float ms[64*65];
    __shared__ float wl[128*64];
    __shared__ float pogs[64], pobs[64];
    int tid = threadIdx.x;
    int l0 = blockIdx.x*64, b = blockIdx.y;
    for (int f = tid; f < 4096; f += 256) {
        int i = f & 63, j = f >> 6;
        ms[i*65 + j] = m[((size_t)b*64 + j)*L4K + l0 + i];
    }
    for (int f = tid; f < 8192; f += 256) wl[f] = bow[f];
    if (tid < 64) { pogs[tid] = pog[tid]; pobs[tid] = pob[tid]; }
    __syncthreads();
    float rs = rsp[0];
    int i = tid & 63, q = tid >> 6;
    float s = 0.f, s2 = 0.f;
    for (int j = 0; j < 64; ++j) { float v = ms[i*65+j]; s += v; s2 = fmaf(v,v,s2); }
    float mn = s*(1.f/64.f);
    float rstd = rsqrtf(s2*(1.f/64.f) - mn*mn + 1e-5f);
    float acc[32];
    #pragma unroll
    for (int cc = 0; cc < 32; ++cc) acc[cc] = bob[q*32+cc];
    for (int j = 0; j < 64; ++j) {
        float v = (ms[i*65+j]-mn)*rstd*pogs[j] + pobs[j];
        #pragma unroll
        for (int cc = 0; cc < 32; ++cc) acc[cc] = fmaf(v, wl[(q*32+cc)*64+j], acc[cc]);
    }
    const float* xb = x + (size_t)b*128*L4K + l0 + i;
    float* ob = outp + (size_t)b*128*L4K + l0 + i;
    unsigned short pk[32];
    #pragma unroll
    for (int cc = 0; cc < 32; ++cc) {
        int c = q*32 + cc;
        float val = 2.f*xb[(size_t)c*L4K] + acc[cc]*rs;
        ob[(size_t)c*L4K] = val;
        pk[cc] = f2b(val);
    }
    uint4* op = (uint4*)&outpb[((size_t)b*L4K + l0 + i)*128 + q*32];
    #pragma unroll
    for (int u = 0; u < 4; ++u) {
        uint4 v;
        v.x = pk[u*8+0] | ((unsigned)pk[u*8+1]<<16);
        v.y = pk[u*8+2] | ((unsigned)pk[u*8+3]<<16);
        v.z = pk[u*8+4] | ((unsigned)pk[u*8+5]<<16);
        v.w = pk[u*8+6] | ((unsigned)pk[u*8+7]<<16);
        op[u] = v;
    }
}

// ---------------- MFMA GEMM: D[l][n] = A[l][k] * W[n][k]^T ----------------
template<int KCHUNKS, bool OUT_BF16>
__global__ __launch_bounds__(256) void gemm_mfma(
    const unsigned short* __restrict__ Ab, const float* __restrict__ Wg,
    void* __restrict__ Dout, int Kpitch, int Npitch)
{
    __shared__ char lds[65536];
    int tid = threadIdx.x;
    int lane = tid & 63, w = tid >> 6;
    int l0 = blockIdx.x * 128, n0 = blockIdx.y * 128, b = blockIdx.z;
    size_t arow0 = (size_t)b*L4K + l0;
    int wm = (w>>1)*64, wn = (w&1)*64;
    f32x4 acc[4][4] = {};
    char* aL = lds;
    char* wL = lds + 32768;
    for (int kc = 0; kc < KCHUNKS; ++kc) {
        if (kc) __syncthreads();
        #pragma unroll
        for (int it = 0; it < 8; ++it) {
            int f = it*256 + tid;
            int row = f >> 4, kp = f & 15;
            uint4 v = *(const uint4*)&Ab[(arow0 + row)*(size_t)Kpitch + kc*128 + kp*8];
            int off = row*256 + kp*16; off ^= (row&7)<<4;
            *(uint4*)(aL + off) = v;
        }
        #pragma unroll
        for (int it = 0; it < 16; ++it) {
            int f = it*256 + tid;
            int row = f >> 5, kg = f & 31;
            float4 v = *(const float4*)&Wg[(size_t)(n0+row)*(KCHUNKS*128) + kc*128 + kg*4];
            uint2 p;
            p.x = f2b(v.x) | ((unsigned)f2b(v.y)<<16);
            p.y = f2b(v.z) | ((unsigned)f2b(v.w)<<16);
            int off = row*256 + kg*8; off ^= (row&7)<<4;
            *(uint2*)(wL + off) = p;
        }
        __syncthreads();
        #pragma unroll
        for (int ks = 0; ks < 4; ++ks) {
            short8 af[4], wf[4];
            int kb = ks*64 + (lane>>4)*16;
            #pragma unroll
            for (int mi = 0; mi < 4; ++mi) {
                int row = wm + mi*16 + (lane&15);
                int off = row*256 + kb; off ^= (row&7)<<4;
                af[mi] = *(const short8*)(aL + off);
            }
            #pragma unroll
            for (int ni = 0; ni < 4; ++ni) {
                int row = wn + ni*16 + (lane&15);
                int off = row*256 + kb; off ^= (row&7)<<4;
                wf[ni] = *(const short8*)(wL + off);
            }
            #pragma unroll
            for (int mi = 0; mi < 4; ++mi)
                #pragma unroll
                for (int ni = 0; ni < 4; ++ni)
                    acc[mi][ni] = __builtin_amdgcn_mfma_f32_16x16x32_bf16(af[mi], wf[ni], acc[mi][ni], 0, 0, 0);
        }
    }
    if (OUT_BF16) {
        __syncthreads();
        unsigned short* cL = (unsigned short*)lds;   // [128][136]
        #pragma unroll
        for (int mi = 0; mi < 4; ++mi)
            #pragma unroll
            for (int ni = 0; ni < 4; ++ni)
                #pragma unroll
                for (int r = 0; r < 4; ++r) {
                    int row = wm + mi*16 + (lane>>4)*4 + r;
                    int col = wn + ni*16 + (lane&15);
                    cL[row*136 + col] = f2b(acc[mi][ni][r]);
                }
        __syncthreads();
        unsigned short* D = (unsigned short*)Dout;
        #pragma unroll
        for (int it = 0; it < 8; ++it) {
            int f = it*256 + tid;
            int row = f >> 4, kp = f & 15;
            uint4 v = *(const uint4*)&cL[row*136 + kp*8];
            *(uint4*)&D[(arow0 + row)*(size_t)Npitch + n0 + kp*8] = v;
        }
    } else {
        float* D = (float*)Dout;
        #pragma unroll
        for (int mi = 0; mi < 4; ++mi)
            #pragma unroll
            for (int ni = 0; ni < 4; ++ni)
                #pragma unroll
                for (int r = 0; r < 4; ++r) {
                    int row = wm + mi*16 + (lane>>4)*4 + r;
                    int col = wn + ni*16 + (lane&15);
                    D[(arow0 + row)*(size_t)Npitch + n0 + col] = acc[mi][ni][r];
                }
    }
}

// ---------------- GN1 stats over bf16 h1t [l][512], 16 ch/group ----------------
__global__ __launch_bounds__(256) void k_gn1stats(
    const unsigned short* __restrict__ h, float* __restrict__ stats)
{
    __shared__ float sred[256], sred2[256];
    int tid = threadIdx.x;
    int b = blockIdx.x >> 5, g = blockIdx.x & 31;
    float s = 0.f, s2 = 0.f;
    for (int it = 0; it < 32; ++it) {
        int f = it*256 + tid;
        int l = f >> 1, half = f & 1;
        uint4 v = *(const uint4*)&h[((size_t)b*L4K + l)*512 + g*16 + half*8];
        unsigned int ws[4] = {v.x, v.y, v.z, v.w};
        #pragma unroll
        for (int u = 0; u < 4; ++u) {
            float a = b2f((unsigned short)(ws[u] & 0xFFFF));
            float c = b2f((unsigned short)(ws[u] >> 16));
            s += a + c; s2 = fmaf(a,a,s2); s2 = fmaf(c,c,s2);
        }
    }
    sred[tid] = s; sred2[tid] = s2; __syncthreads();
    for (int off = 128; off; off >>= 1) {
        if (tid < off) { sred[tid] += sred[tid+off]; sred2[tid] += sred2[tid+off]; }
        __syncthreads();
    }
    if (tid == 0) {
        float inv = 1.f/65536.f;
        float mn = sred[0]*inv;
        float var = sred2[0]*inv - mn*mn;
        stats[blockIdx.x*2]   = mn;
        stats[blockIdx.x*2+1] = rsqrtf(var + 1e-5f);
    }
}

// ---------------- K9: gn1 apply + exact gelu, in-place bf16 [l][512] --------
__global__ __launch_bounds__(256) void k9_gngelu(
    unsigned short* __restrict__ h, const float* __restrict__ stats,
    const float* __restrict__ g1, const float* __restrict__ b1)
{
    size_t idx = ((size_t)blockIdx.x*256 + threadIdx.x)*8;
    int o0 = (int)(idx & 511);
    int b = (int)(idx >> 21);
    int sg = b*32 + (o0 >> 4);
    float mn = stats[sg*2], rstd = stats[sg*2+1];
    uint4 v = *(uint4*)&h[idx];
    unsigned int ws[4] = {v.x, v.y, v.z, v.w};
    unsigned int out[4];
    #pragma unroll
    for (int u = 0; u < 4; ++u) {
        float a = b2f((unsigned short)(ws[u] & 0xFFFF));
        float c = b2f((unsigned short)(ws[u] >> 16));
        int o = o0 + u*2;
        float ta = (a-mn)*rstd*g1[o]   + b1[o];
        float tc = (c-mn)*rstd*g1[o+1] + b1[o+1];
        ta = 0.5f*ta*(1.f + erff(ta*0.70710678118654752f));
        tc = 0.5f*tc*(1.f + erff(tc*0.70710678118654752f));
        out[u] = f2b(ta) | ((unsigned)f2b(tc)<<16);
    }
    uint4 r; r.x = out[0]; r.y = out[1]; r.z = out[2]; r.w = out[3];
    *(uint4*)&h[idx] = r;
}

// ---------------- GN2 stats over fp32 h2t [l][128], 4 ch/group ----------------
__global__ __launch_bounds__(256) void k_gn2stats(
    const float* __restrict__ h, float* __restrict__ stats)
{
    __shared__ float sred[256], sred2[256];
    int tid = threadIdx.x;
    int b = blockIdx.x >> 5, g = blockIdx.x & 31;
    float s = 0.f, s2 = 0.f;
    for (int it = 0; it < 16; ++it) {
        int l = it*256 + tid;
        float4 v = ((const float4*)h)[((size_t)b*L4K + l)*32 + g];
        s += v.x+v.y+v.z+v.w;
        s2 = fmaf(v.x,v.x,s2); s2 = fmaf(v.y,v.y,s2); s2 = fmaf(v.z,v.z,s2); s2 = fmaf(v.w,v.w,s2);
    }
    sred[tid] = s; sred2[tid] = s2; __syncthreads();
    for (int off = 128; off; off >>= 1) {
        if (tid < off) { sred[tid] += sred[tid+off]; sred2[tid] += sred2[tid+off]; }
        __syncthreads();
    }
    if (tid == 0) {
        float inv = 1.f/16384.f;
        float mn = sred[0]*inv;
        float var = sred2[0]*inv - mn*mn;
        stats[blockIdx.x*2]   = mn;
        stats[blockIdx.x*2+1] = rsqrtf(var + 1e-5f);
    }
}

// ---------------- K12: out[c][l] = outp[c][l] + gn2(h2t[l][c]) (transpose) ----
__global__ __launch_bounds__(256) void k12_final(
    const float* __restrict__ outp, const float* __restrict__ h2t,
    const float* __restrict__ stats, const float* __restrict__ g2,
    const float* __restrict__ b2, float* __restrict__ out)
{
    __shared__ float T[32*33];
    int tid = threadIdx.x;
    int l0 = blockIdx.x*32, c0 = blockIdx.y*32, b = blockIdx.z;
    {
        int i = tid >> 3, jq = tid & 7;
        float4 v = ((const float4*)h2t)[((size_t)b*L4K + l0 + i)*32 + (c0>>2) + jq];
        int sg = b*32 + (c0>>2) + jq;
        float mn = stats[sg*2], rstd = stats[sg*2+1];
        int c = c0 + jq*4;
        T[(jq*4+0)*33 + i] = (v.x-mn)*rstd*g2[c+0] + b2[c+0];
        T[(jq*4+1)*33 + i] = (v.y-mn)*rstd*g2[c+1] + b2[c+1];
        T[(jq*4+2)*33 + i] = (v.z-mn)*rstd*g2[c+2] + b2[c+2];
        T[(jq*4+3)*33 + i] = (v.w-mn)*rstd*g2[c+3] + b2[c+3];
    }
    __syncthreads();
    {
        int c = tid >> 3, iq = tid & 7;
        size_t gi = ((size_t)b*128 + c0 + c)*1024 + (l0>>2) + iq;
        float4 o = ((const float4*)outp)[gi];
        float4 r;
        r.x = o.x + T[c*33 + iq*4 + 0];
        r.y = o.y + T[c*33 + iq*4 + 1];
        r.z = o.z + T[c*33 + iq*4 + 2];
        r.w = o.w + T[c*33 + iq*4 + 3];
        ((float4*)out)[gi] = r;
    }
}

extern "C" void kernel_launch(void* const* d_in, const int* in_sizes, int n_in,
                              void* d_out, int out_size, void* d_ws, size_t ws_size,
                              hipStream_t stream) {
    (void)in_sizes; (void)n_in; (void)out_size; (void)ws_size;
    const float* x    = (const float*)d_in[0];
    const float* png  = (const float*)d_in[1];
    const float* pnb  = (const float*)d_in[2];
    const float* biw  = (const float*)d_in[3];
    const float* bib  = (const float*)d_in[4];
    const float* ipw  = (const float*)d_in[5];
    const float* cw   = (const float*)d_in[6];
    const float* cb   = (const float*)d_in[7];
    const float* xpw  = (const float*)d_in[8];
    const float* dtw  = (const float*)d_in[9];
    const float* dtb  = (const float*)d_in[10];
    const float* alog = (const float*)d_in[11];
    const float* Dp   = (const float*)d_in[12];
    const float* opw  = (const float*)d_in[13];
    const float* pog  = (const float*)d_in[14];
    const float* pob  = (const float*)d_in[15];
    const float* bow  = (const float*)d_in[16];
    const float* bob  = (const float*)d_in[17];
    const float* rsp  = (const float*)d_in[18];
    const float* f1w  = (const float*)d_in[19];
    const float* g1g  = (const float*)d_in[20];
    const float* g1b  = (const float*)d_in[21];
    const float* f2w  = (const float*)d_in[22];
    const float* g2g  = (const float*)d_in[23];
    const float* g2b  = (const float*)d_in[24];

    char* ws = (char*)d_ws;
    // Phase 1 (mamba), peak 112 MiB. All [n][feature][4096] planes.
    float* S    = (float*)(ws + 0);            // 64 MB, dead after k5
    float* zc   = (float*)(ws + 67108864);     // 8 MB,  dead after k5
    float* zg   = (float*)(ws + 75497472);     // 16 MB, dead after k5
    float* xcp  = (float*)(ws + 92274688);     // 16 MB, dead after k2
    float* y    = (float*)(ws + 92274688);     // aliases xcp
    float* m    = (float*)(ws + 109051904);    // 8 MB (k5->k6)
    float* chA  = (float*)(ws + 109051904);                // 2 MB (pre-k5)
    float* chH  = (float*)(ws + 109051904 + 2097152);      // 2 MB
    float* hst  = (float*)(ws + 109051904 + 4194304);      // 2 MB
    // Phase 2 (post): all alias dead phase-1 regions
    float*          outp  = (float*)(ws + 0);              // 16 MB fp32 [c][l]
    unsigned short* outpb = (unsigned short*)(ws + 16777216); // 8 MB bf16 [l][c]
    unsigned short* h1tb  = (unsigned short*)(ws + 25165824); // 32 MB bf16 [l][512]
    float*          h2t   = (float*)(ws + 58720256);       // 16 MB fp32 [l][128]
    float*          st1   = (float*)(ws + 75497472);       // 2 KB (zg dead)
    float*          st2   = (float*)(ws + 75501568);

    k1_pre<<<dim3(128,8),256,0,stream>>>(x,png,pnb,biw,bib,ipw,zc,xcp,zg);
    k2_conv<<<dim3(32,32),256,0,stream>>>(xcp,cw,cb,xpw,dtw,dtb,S);
    k3a_local<<<dim3(NCH,32),512,0,stream>>>(S,alog,chA,chH);
    k3b_prefix<<<64,256,0,stream>>>(chA,chH,hst);
    k3c_emit<<<dim3(NCH,32),512,0,stream>>>(S,alog,hst,y);
    k5_out<<<1024,256,0,stream>>>(y,S,zg,zc,Dp,opw,m);
    k6_post<<<dim3(64,8),256,0,stream>>>(m,x,pog,pob,bow,bob,rsp,outp,outpb);
    gemm_mfma<1,true><<<dim3(32,4,8),256,0,stream>>>(outpb,f1w,(void*)h1tb,128,512);
    k_gn1stats<<<256,256,0,stream>>>(h1tb,st1);
    k9_gngelu<<<8192,256,0,stream>>>(h1tb,st1,g1g,g1b);
    gemm_mfma<4,false><<<dim3(32,1,8),256,0,stream>>>(h1tb,f2w,(void*)h2t,512,128);
    k_gn2stats<<<256,256,0,stream>>>(h2t,st2);
    k12_final<<<dim3(128,4,8),256,0,stream>>>(outp,h2t,st2,g2g,g2b,(float*)d_out);
}

// Round 12
// 381.271 us; speedup vs baseline: 1.0437x; 1.0437x over previous
//
#include <hip/hip_runtime.h>
#include <hip/hip_bf16.h>
#include <math.h>

#define L4K 4096
#define NCH 32     // scan chunks over L
#define CL  128    // timesteps per chunk
#define SPN (128*4096)   // floats per n in S planes

typedef __attribute__((ext_vector_type(8))) short short8;
typedef __attribute__((ext_vector_type(4))) float f32x4;

__device__ __forceinline__ unsigned short f2b(float f) {
    unsigned int u = __float_as_uint(f);
    unsigned int r = u + 0x7FFFu + ((u >> 16) & 1u);
    return (unsigned short)(r >> 16);
}
__device__ __forceinline__ float b2f(unsigned short h) {
    return __uint_as_float(((unsigned int)h) << 16);
}
// sum over each 16-lane row via fused v_add_f32_dpp (bound_ctrl=true enables combine)
__device__ __forceinline__ float rowsum16(float p) {
    int t;
    t = __builtin_amdgcn_update_dpp(0, __float_as_int(p), 0x128, 0xf, 0xf, true);
    p += __int_as_float(t);
    t = __builtin_amdgcn_update_dpp(0, __float_as_int(p), 0x124, 0xf, 0xf, true);
    p += __int_as_float(t);
    t = __builtin_amdgcn_update_dpp(0, __float_as_int(p), 0x122, 0xf, 0xf, true);
    p += __int_as_float(t);
    t = __builtin_amdgcn_update_dpp(0, __float_as_int(p), 0x121, 0xf, 0xf, true);
    p += __int_as_float(t);
    return p;
}

// ---------------- K1: pre-LN + bott_in + in_proj (plane outputs) ----------------
__global__ __launch_bounds__(256) void k1_pre(
    const float* __restrict__ x, const float* __restrict__ png, const float* __restrict__ pnb,
    const float* __restrict__ biw, const float* __restrict__ bib, const float* __restrict__ ipw,
    float* __restrict__ zc, float* __restrict__ xcp, float* __restrict__ zg)
{
    __shared__ float xs[128*32];
    __shared__ float wl[64*128];
    __shared__ float zs[32*65];
    __shared__ float ipl[64*16];
    __shared__ float pngs[128], pnbs[128];
    int tid = threadIdx.x;
    int l0 = blockIdx.x*32, b = blockIdx.y;
    const float* xb = x + (size_t)b*128*L4K;
    for (int it = 0; it < 16; ++it) {
        int f = it*256 + tid; int c = f>>5, i = f&31;
        xs[f] = xb[(size_t)c*L4K + l0 + i];
    }
    for (int f = tid; f < 8192; f += 256) wl[f] = biw[f];
    for (int f = tid; f < 1024; f += 256) ipl[f] = ipw[f];
    if (tid < 128) { pngs[tid] = png[tid]; pnbs[tid] = pnb[tid]; }
    __syncthreads();
    int i = tid & 31, q = tid >> 5;
    float s = 0.f, s2 = 0.f;
    for (int c = 0; c < 128; ++c) { float v = xs[c*32+i]; s += v; s2 = fmaf(v,v,s2); }
    float mn = s*(1.f/128.f);
    float rstd = rsqrtf(s2*(1.f/128.f) - mn*mn + 1e-5f);
    float z[8];
    #pragma unroll
    for (int jj = 0; jj < 8; ++jj) z[jj] = bib[q*8+jj];
    for (int c = 0; c < 128; ++c) {
        float xv = (xs[c*32+i] - mn)*rstd*pngs[c] + pnbs[c];
        #pragma unroll
        for (int jj = 0; jj < 8; ++jj) z[jj] = fmaf(xv, wl[(q*8+jj)*128 + c], z[jj]);
    }
    #pragma unroll
    for (int jj = 0; jj < 8; ++jj) zs[i*65 + q*8 + jj] = z[jj];
    __syncthreads();
    if (tid < 128) {
        int i2 = tid & 31, g = tid >> 5;
        int n = g*8 + b; int l = l0 + i2;
        float zv[16];
        #pragma unroll
        for (int k = 0; k < 16; ++k) zv[k] = zs[i2*65 + g*16 + k];
        float* zcb = zc + ((size_t)n*16)*L4K + l;
        #pragma unroll
        for (int k = 0; k < 16; ++k) zcb[(size_t)k*L4K] = zv[k];
        float* xo = xcp + ((size_t)n*32)*L4K + l;
        float* zo = zg  + ((size_t)n*32)*L4K + l;
        #pragma unroll
        for (int o = 0; o < 64; ++o) {
            float a = 0.f;
            #pragma unroll
            for (int k = 0; k < 16; ++k) a = fmaf(zv[k], ipl[o*16+k], a);
            if (o < 32) xo[(size_t)o*L4K] = a; else zo[(size_t)(o-32)*L4K] = a;
        }
    }
}

// ---------------- K2: conv + silu + x_proj + dt -> S planes (SGPR weights) ----
// One thread per t; xc[32] in VGPRs; all weights via scalar loads (wave-uniform).
// S planes per n (stride SPN): [0:32)=dt, [32:64)=dx, [64:80)=B, [80:96)=C, [96:128)=xc
__global__ __launch_bounds__(128) void k2_conv(
    const float* __restrict__ xcp, const float* __restrict__ cw, const float* __restrict__ cb,
    const float* __restrict__ xpw, const float* __restrict__ dtw, const float* __restrict__ dtb,
    float* __restrict__ S)
{
    __shared__ float xt[131*33];    // [r][d], r = t-3..t+127 local
    int tid = threadIdx.x;
    int t0 = blockIdx.x*128; int n = blockIdx.y;
    const float* xb = xcp + (size_t)n*32*L4K;
    #pragma unroll 4
    for (int d = 0; d < 32; ++d) {
        int t = t0 - 3 + tid;
        xt[tid*33 + d] = (t >= 0) ? xb[(size_t)d*L4K + t] : 0.f;
        if (tid < 3) xt[(128+tid)*33 + d] = xb[(size_t)d*L4K + t0 + 125 + tid];
    }
    __syncthreads();
    // conv + silu -> xc[32] in registers
    float xc[32];
    #pragma unroll
    for (int d = 0; d < 32; ++d) {
        float sv = cb[d];
        #pragma unroll
        for (int k = 0; k < 4; ++k) sv = fmaf(cw[d*4+k], xt[(tid+k)*33 + d], sv);
        float e = __expf(-sv);
        xc[d] = __fdividef(sv, 1.f + e);
    }
    float* Sn = S + (size_t)n*SPN + t0 + tid;
    // dt row (row 0 of x_proj)
    float dtr = 0.f;
    #pragma unroll
    for (int dd = 0; dd < 32; ++dd) dtr = fmaf(xc[dd], xpw[dd], dtr);
    // softplus + dt/dx/xc planes
    #pragma unroll
    for (int d = 0; d < 32; ++d) {
        float dv = fmaf(dtr, dtw[d], dtb[d]);
        float e = __expf(-fabsf(dv));
        float sp = fmaxf(dv, 0.f) + __logf(1.f + e);
        Sn[(size_t)d*L4K]      = sp;
        Sn[(size_t)(32+d)*L4K] = sp * xc[d];
        Sn[(size_t)(96+d)*L4K] = xc[d];
    }
    // B rows (1..16) and C rows (17..32)
    #pragma unroll
    for (int o = 0; o < 16; ++o) {
        float a = 0.f;
        #pragma unroll
        for (int dd = 0; dd < 32; ++dd) a = fmaf(xc[dd], xpw[(1+o)*32+dd], a);
        Sn[(size_t)(64+o)*L4K] = a;
    }
    #pragma unroll
    for (int o = 0; o < 16; ++o) {
        float a = 0.f;
        #pragma unroll
        for (int dd = 0; dd < 32; ++dd) a = fmaf(xc[dd], xpw[(17+o)*32+dd], a);
        Sn[(size_t)(80+o)*L4K] = a;
    }
}

// ---------------- K3a: chunk-local scan (LDS pair-staged) ----------------
__global__ __launch_bounds__(512) void k3a_local(
    const float* __restrict__ S, const float* __restrict__ alog,
    float* __restrict__ chunkA, float* __restrict__ chunkH)
{
    __shared__ float2 pDT[32*130];   // (dt,dx)[d][t], stride 130
    __shared__ float  pB[16*132];    // B[s][t], stride 132
    int tid = threadIdx.x;
    int d = tid >> 4, s = tid & 15;
    int chunk = blockIdx.x, n = blockIdx.y;
    float A = -__expf(alog[d*16 + s]);
    const float* base = S + (size_t)n*SPN + (size_t)chunk*CL;
    {   // stage (dt,dx) pairs: thread = (sd, j), 8 t each
        int sd = tid >> 4, j = tid & 15;
        const float* dtp = base + (size_t)sd*L4K + j*8;
        const float* dxp = base + (size_t)(32+sd)*L4K + j*8;
        float4 a0 = *(const float4*)(dtp);
        float4 a1 = *(const float4*)(dtp+4);
        float4 b0 = *(const float4*)(dxp);
        float4 b1 = *(const float4*)(dxp+4);
        float2* w = pDT + sd*130 + j*8;
        *(float4*)(w+0) = make_float4(a0.x,b0.x,a0.y,b0.y);
        *(float4*)(w+2) = make_float4(a0.z,b0.z,a0.w,b0.w);
        *(float4*)(w+4) = make_float4(a1.x,b1.x,a1.y,b1.y);
        *(float4*)(w+6) = make_float4(a1.z,b1.z,a1.w,b1.w);
    }
    if (tid < 256) {   // stage B singles: thread = (ss, j), 8 t each
        int ss = tid >> 4, j = tid & 15;
        const float* bp = base + (size_t)(64+ss)*L4K + j*8;
        float4 v0 = *(const float4*)(bp);
        float4 v1 = *(const float4*)(bp+4);
        float* w = pB + ss*132 + j*8;
        *(float4*)(w+0) = v0;
        *(float4*)(w+4) = v1;
    }
    __syncthreads();
    float h = 0.f, ap = 1.f;
    #pragma unroll 4
    for (int t = 0; t < CL; ++t) {
        float2 dd = pDT[d*130 + t];
        float Bv = pB[s*132 + t];
        float dA = __expf(dd.x * A);
        h = fmaf(dA, h, dd.y * Bv);
        ap *= dA;
    }
    size_t idx = (size_t)chunk*16384 + n*512 + tid;
    chunkA[idx] = ap;
    chunkH[idx] = h;
}

// ---------------- K3b: prefix across chunks ----------------
__global__ __launch_bounds__(256) void k3b_prefix(
    const float* __restrict__ chunkA, const float* __restrict__ chunkH,
    float* __restrict__ hstart)
{
    int nds = blockIdx.x*256 + threadIdx.x;
    float h = 0.f;
    hstart[nds] = 0.f;
    for (int c = 0; c < NCH-1; ++c) {
        h = fmaf(h, chunkA[(size_t)c*16384 + nds], chunkH[(size_t)c*16384 + nds]);
        hstart[(size_t)(c+1)*16384 + nds] = h;
    }
}

// ---------------- K3c: recompute with start state, emit y planes ------------
__global__ __launch_bounds__(512) void k3c_emit(
    const float* __restrict__ S, const float* __restrict__ alog,
    const float* __restrict__ hstart, float* __restrict__ y)
{
    __shared__ float2 pDT[32*130];   // (dt,dx)[d][t]
    __shared__ float2 pBC[16*130];   // (B,C)[s][t]
    int tid = threadIdx.x;
    int d = tid >> 4, s = tid & 15;
    int chunk = blockIdx.x, n = blockIdx.y;
    float A = -__expf(alog[d*16 + s]);
    const float* base = S + (size_t)n*SPN + (size_t)chunk*CL;
    float h = hstart[(size_t)chunk*16384 + n*512 + tid];
    {   // stage (dt,dx)
        int sd = tid >> 4, j = tid & 15;
        const float* dtp = base + (size_t)sd*L4K + j*8;
        const float* dxp = base + (size_t)(32+sd)*L4K + j*8;
        float4 a0 = *(const float4*)(dtp);
        float4 a1 = *(const float4*)(dtp+4);
        float4 b0 = *(const float4*)(dxp);
        float4 b1 = *(const float4*)(dxp+4);
        float2* w = pDT + sd*130 + j*8;
        *(float4*)(w+0) = make_float4(a0.x,b0.x,a0.y,b0.y);
        *(float4*)(w+2) = make_float4(a0.z,b0.z,a0.w,b0.w);
        *(float4*)(w+4) = make_float4(a1.x,b1.x,a1.y,b1.y);
        *(float4*)(w+6) = make_float4(a1.z,b1.z,a1.w,b1.w);
    }
    if (tid < 256) {   // stage (B,C)
        int ss = tid >> 4, j = tid & 15;
        const float* bp = base + (size_t)(64+ss)*L4K + j*8;
        const float* cp = base + (size_t)(80+ss)*L4K + j*8;
        float4 v0 = *(const float4*)(bp);
        float4 v1 = *(const float4*)(bp+4);
        float4 c0 = *(const float4*)(cp);
        float4 c1 = *(const float4*)(cp+4);
        float2* w = pBC + ss*130 + j*8;
        *(float4*)(w+0) = make_float4(v0.x,c0.x,v0.y,c0.y);
        *(float4*)(w+2) = make_float4(v0.z,c0.z,v0.w,c0.w);
        *(float4*)(w+4) = make_float4(v1.x,c1.x,v1.y,c1.y);
        *(float4*)(w+6) = make_float4(v1.z,c1.z,v1.w,c1.w);
    }
    __syncthreads();
    float4* yb = (float4*)(y + ((size_t)n*32 + d)*L4K + (size_t)chunk*CL);
    for (int i = 0; i < CL/4; ++i) {
        float4 yv;
        #pragma unroll
        for (int u = 0; u < 4; ++u) {
            int t = i*4 + u;
            float2 dd = pDT[d*130 + t];
            float2 bc = pBC[s*130 + t];
            float dA = __expf(dd.x * A);
            h = fmaf(dA, h, dd.y * bc.x);
            ((float*)&yv)[u] = rowsum16(h * bc.y);
        }
        if (s == 0) yb[i] = yv;
    }
}

// ---------------- K5: gate + out_proj + residual -> m planes (split halves) --
__global__ __launch_bounds__(256) void k5_out(
    const float* __restrict__ y, const float* __restrict__ S, const float* __restrict__ zg,
    const float* __restrict__ zc, const float* __restrict__ Dp, const float* __restrict__ opw,
    float* __restrict__ m)
{
    __shared__ float vs[128*33];
    int tid = threadIdx.x;
    int tl = tid & 127, p = tid >> 7;
    int id = blockIdx.x*128 + tl;     // (n,t) pair
    int n = id >> 12, t = id & 4095;
    const float* yb  = y  + (size_t)n*32*L4K + t;
    const float* xcb = S  + (size_t)n*SPN + (size_t)96*L4K + t;
    const float* zgb = zg + (size_t)n*32*L4K + t;
    const float* zcb = zc + (size_t)n*16*L4K + t;
    #pragma unroll
    for (int dd2 = 0; dd2 < 16; ++dd2) {
        int dd = p*16 + dd2;
        float g = zgb[(size_t)dd*L4K];
        float sig = 1.f/(1.f + __expf(-g));
        vs[tl*33 + dd] = (yb[(size_t)dd*L4K] + xcb[(size_t)dd*L4K]*Dp[dd]) * (g*sig);
    }
    __syncthreads();
    int b = n & 7, g4 = n >> 3;
    float* mp = m + ((size_t)b*64 + g4*16)*L4K + t;
    #pragma unroll
    for (int jj = 0; jj < 8; ++jj) {
        int j = p*8 + jj;
        float a = zcb[(size_t)j*L4K];
        #pragma unroll
        for (int dd = 0; dd < 32; ++dd) a = fmaf(vs[tl*33+dd], opw[j*32+dd], a);
        mp[(size_t)j*L4K] = a;
    }
}

// ---------------- K6: post-LN + bott_out; outp fp32 [c][l] + bf16 [l][c] ----
__global__ __launch_bounds__(256) void k6_post(
    const float* __restrict__ m, const float* __restrict__ x,
    const float* __restrict__ pog, const float* __restrict__ pob,
    const float* __restrict__ bow, const float* __restrict__ bob,
    const float* __restrict__ rsp, float* __restrict__ outp,
    unsigned short* __restrict__ outpb)
{
    __shared__ float ms[64*65];
    __shared__ float wl[128*64];
    __shared__ float pogs[64], pobs[64];
    int tid = threadIdx.x;
    int l0 = blockIdx.x*64, b = blockIdx.y;
    for (int f = tid; f < 4096; f += 256) {
        int i = f & 63, j = f >> 6;
        ms[i*65 + j] = m[((size_t)b*64 + j)*L4K + l0 + i];
    }
    for (int f = tid; f < 8192; f += 256) wl[f] = bow[f];
    if (tid < 64) { pogs[tid] = pog[tid]; pobs[tid] = pob[tid]; }
    __syncthreads();
    float rs = rsp[0];
    int i = tid & 63, q = tid >> 6;
    float s = 0.f, s2 = 0.f;
    for (int j = 0; j < 64; ++j) { float v = ms[i*65+j]; s += v; s2 = fmaf(v,v,s2); }
    float mn = s*(1.f/64.f);
    float rstd = rsqrtf(s2*(1.f/64.f) - mn*mn + 1e-5f);
    float acc[32];
    #pragma unroll
    for (int cc = 0; cc < 32; ++cc) acc[cc] = bob[q*32+cc];
    for (int j = 0; j < 64; ++j) {
        float v = (ms[i*65+j]-mn)*rstd*pogs[j] + pobs[j];
        #pragma unroll
        for (int cc = 0; cc < 32; ++cc) acc[cc] = fmaf(v, wl[(q*32+cc)*64+j], acc[cc]);
    }
    const float* xb = x + (size_t)b*128*L4K + l0 + i;
    float* ob = outp + (size_t)b*128*L4K + l0 + i;
    unsigned short pk[32];
    #pragma unroll
    for (int cc = 0; cc < 32; ++cc) {
        int c = q*32 + cc;
        float val = 2.f*xb[(size_t)c*L4K] + acc[cc]*rs;
        ob[(size_t)c*L4K] = val;
        pk[cc] = f2b(val);
    }
    uint4* op = (uint4*)&outpb[((size_t)b*L4K + l0 + i)*128 + q*32];
    #pragma unroll
    for (int u = 0; u < 4; ++u) {
        uint4 v;
        v.x = pk[u*8+0] | ((unsigned)pk[u*8+1]<<16);
        v.y = pk[u*8+2] | ((unsigned)pk[u*8+3]<<16);
        v.z = pk[u*8+4] | ((unsigned)pk[u*8+5]<<16);
        v.w = pk[u*8+6] | ((unsigned)pk[u*8+7]<<16);
        op[u] = v;
    }
}

// ---------------- MFMA GEMM: D[l][n] = A[l][k] * W[n][k]^T ----------------
// BM = M-tile rows (64 or 128); N-tile fixed 128.
template<int KCHUNKS, int BM, bool OUT_BF16>
__global__ __launch_bounds__(256) void gemm_mfma(
    const unsigned short* __restrict__ Ab, const float* __restrict__ Wg,
    void* __restrict__ Dout, int Kpitch, int Npitch)
{
    __shared__ char lds[BM*256 + 32768];
    constexpr int MI = BM/32;
    int tid = threadIdx.x;
    int lane = tid & 63, w = tid >> 6;
    int l0 = blockIdx.x * BM, n0 = blockIdx.y * 128, b = blockIdx.z;
    size_t arow0 = (size_t)b*L4K + l0;
    int wm = (w>>1)*(BM/2), wn = (w&1)*64;
    f32x4 acc[MI][4] = {};
    char* aL = lds;
    char* wL = lds + BM*256;
    for (int kc = 0; kc < KCHUNKS; ++kc) {
        if (kc) __syncthreads();
        #pragma unroll
        for (int it = 0; it < BM/16; ++it) {
            int f = it*256 + tid;
            int row = f >> 4, kp = f & 15;
            uint4 v = *(const uint4*)&Ab[(arow0 + row)*(size_t)Kpitch + kc*128 + kp*8];
            int off = row*256 + kp*16; off ^= (row&7)<<4;
            *(uint4*)(aL + off) = v;
        }
        #pragma unroll
        for (int it = 0; it < 16; ++it) {
            int f = it*256 + tid;
            int row = f >> 5, kg = f & 31;
            float4 v = *(const float4*)&Wg[(size_t)(n0+row)*(KCHUNKS*128) + kc*128 + kg*4];
            uint2 p;
            p.x = f2b(v.x) | ((unsigned)f2b(v.y)<<16);
            p.y = f2b(v.z) | ((unsigned)f2b(v.w)<<16);
            int off = row*256 + kg*8; off ^= (row&7)<<4;
            *(uint2*)(wL + off) = p;
        }
        __syncthreads();
        #pragma unroll
        for (int ks = 0; ks < 4; ++ks) {
            short8 af[MI], wf[4];
            int kb = ks*64 + (lane>>4)*16;
            #pragma unroll
            for (int mi = 0; mi < MI; ++mi) {
                int row = wm + mi*16 + (lane&15);
                int off = row*256 + kb; off ^= (row&7)<<4;
                af[mi] = *(const short8*)(aL + off);
            }
            #pragma unroll
            for (int ni = 0; ni < 4; ++ni) {
                int row = wn + ni*16 + (lane&15);
                int off = row*256 + kb; off ^= (row&7)<<4;
                wf[ni] = *(const short8*)(wL + off);
            }
            #pragma unroll
            for (int mi = 0; mi < MI; ++mi)
                #pragma unroll
                for (int ni = 0; ni < 4; ++ni)
                    acc[mi][ni] = __builtin_amdgcn_mfma_f32_16x16x32_bf16(af[mi], wf[ni], acc[mi][ni], 0, 0, 0);
        }
    }
    if (OUT_BF16) {
        __syncthreads();
        unsigned short* cL = (unsigned short*)lds;   // [BM][136]
        #pragma unroll
        for (int mi = 0; mi < MI; ++mi)
            #pragma unroll
            for (int ni = 0; ni < 4; ++ni)
                #pragma unroll
                for (int r = 0; r < 4; ++r) {
                    int row = wm + mi*16 + (lane>>4)*4 + r;
                    int col = wn + ni*16 + (lane&15);
                    cL[row*136 + col] = f2b(acc[mi][ni][r]);
                }
        __syncthreads();
        unsigned short* D = (unsigned short*)Dout;
        #pragma unroll
        for (int it = 0; it < BM/16; ++it) {
            int f = it*256 + tid;
            int row = f >> 4, kp = f & 15;
            uint4 v = *(const uint4*)&cL[row*136 + kp*8];
            *(uint4*)&D[(arow0 + row)*(size_t)Npitch + n0 + kp*8] = v;
        }
    } else {
        float* D = (float*)Dout;
        #pragma unroll
        for (int mi = 0; mi < MI; ++mi)
            #pragma unroll
            for (int ni = 0; ni < 4; ++ni)
                #pragma unroll
                for (int r = 0; r < 4; ++r) {
                    int row = wm + mi*16 + (lane>>4)*4 + r;
                    int col = wn + ni*16 + (lane&15);
                    D[(arow0 + row)*(size_t)Npitch + n0 + col] = acc[mi][ni][r];
                }
    }
}

// ---------------- GN1 stats over bf16 h1t [l][512], 16 ch/group ----------------
__global__ __launch_bounds__(256) void k_gn1stats(
    const unsigned short* __restrict__ h, float* __restrict__ stats)
{
    __shared__ float sred[256], sred2[256];
    int tid = threadIdx.x;
    int b = blockIdx.x >> 5, g = blockIdx.x & 31;
    float s = 0.f, s2 = 0.f;
    for (int it = 0; it < 32; ++it) {
        int f = it*256 + tid;
        int l = f >> 1, half = f & 1;
        uint4 v = *(const uint4*)&h[((size_t)b*L4K + l)*512 + g*16 + half*8];
        unsigned int ws[4] = {v.x, v.y, v.z, v.w};
        #pragma unroll
        for (int u = 0; u < 4; ++u) {
            float a = b2f((unsigned short)(ws[u] & 0xFFFF));
            float c = b2f((unsigned short)(ws[u] >> 16));
            s += a + c; s2 = fmaf(a,a,s2); s2 = fmaf(c,c,s2);
        }
    }
    sred[tid] = s; sred2[tid] = s2; __syncthreads();
    for (int off = 128; off; off >>= 1) {
        if (tid < off) { sred[tid] += sred[tid+off]; sred2[tid] += sred2[tid+off]; }
        __syncthreads();
    }
    if (tid == 0) {
        float inv = 1.f/65536.f;
        float mn = sred[0]*inv;
        float var = sred2[0]*inv - mn*mn;
        stats[blockIdx.x*2]   = mn;
        stats[blockIdx.x*2+1] = rsqrtf(var + 1e-5f);
    }
}

// ---------------- K9: gn1 apply + tanh-gelu, in-place bf16 [l][512] --------
__global__ __launch_bounds__(256) void k9_gngelu(
    unsigned short* __restrict__ h, const float* __restrict__ stats,
    const float* __restrict__ g1, const float* __restrict__ b1)
{
    size_t idx = ((size_t)blockIdx.x*256 + threadIdx.x)*8;
    int o0 = (int)(idx & 511);
    int b = (int)(idx >> 21);
    int sg = b*32 + (o0 >> 4);
    float mn = stats[sg*2], rstd = stats[sg*2+1];
    uint4 v = *(uint4*)&h[idx];
    unsigned int ws[4] = {v.x, v.y, v.z, v.w};
    unsigned int out[4];
    #pragma unroll
    for (int u = 0; u < 4; ++u) {
        float a = b2f((unsigned short)(ws[u] & 0xFFFF));
        float c = b2f((unsigned short)(ws[u] >> 16));
        int o = o0 + u*2;
        float ta = (a-mn)*rstd*g1[o]   + b1[o];
        float tc = (c-mn)*rstd*g1[o+1] + b1[o+1];
        // tanh-form gelu (err ~3e-4 abs, well within threshold)
        float za = 0.7978845608f*fmaf(0.044715f*ta, ta*ta, ta);
        float zc2 = 0.7978845608f*fmaf(0.044715f*tc, tc*tc, tc);
        float ea = __expf(-2.f*za), ec = __expf(-2.f*zc2);
        ta = ta * __fdividef(1.f, 1.f + ea);
        tc = tc * __fdividef(1.f, 1.f + ec);
        out[u] = f2b(ta) | ((unsigned)f2b(tc)<<16);
    }
    uint4 r; r.x = out[0]; r.y = out[1]; r.z = out[2]; r.w = out[3];
    *(uint4*)&h[idx] = r;
}

// ---------------- GN2 stats over fp32 h2t [l][128], 4 ch/group ----------------
__global__ __launch_bounds__(256) void k_gn2stats(
    const float* __restrict__ h, float* __restrict__ stats)
{
    __shared__ float sred[256], sred2[256];
    int tid = threadIdx.x;
    int b = blockIdx.x >> 5, g = blockIdx.x & 31;
    float s = 0.f, s2 = 0.f;
    for (int it = 0; it < 16; ++it) {
        int l = it*256 + tid;
        float4 v = ((const float4*)h)[((size_t)b*L4K + l)*32 + g];
        s += v.x+v.y+v.z+v.w;
        s2 = fmaf(v.x,v.x,s2); s2 = fmaf(v.y,v.y,s2); s2 = fmaf(v.z,v.z,s2); s2 = fmaf(v.w,v.w,s2);
    }
    sred[tid] = s; sred2[tid] = s2; __syncthreads();
    for (int off = 128; off; off >>= 1) {
        if (tid < off) { sred[tid] += sred[tid+off]; sred2[tid] += sred2[tid+off]; }
        __syncthreads();
    }
    if (tid == 0) {
        float inv = 1.f/16384.f;
        float mn = sred[0]*inv;
        float var = sred2[0]*inv - mn*mn;
        stats[blockIdx.x*2]   = mn;
        stats[blockIdx.x*2+1] = rsqrtf(var + 1e-5f);
    }
}

// ---------------- K12: out[c][l] = outp[c][l] + gn2(h2t[l][c]) (transpose) ----
__global__ __launch_bounds__(256) void k12_final(
    const float* __restrict__ outp, const float* __restrict__ h2t,
    const float* __restrict__ stats, const float* __restrict__ g2,
    const float* __restrict__ b2, float* __restrict__ out)
{
    __shared__ float T[32*33];
    int tid = threadIdx.x;
    int l0 = blockIdx.x*32, c0 = blockIdx.y*32, b = blockIdx.z;
    {
        int i = tid >> 3, jq = tid & 7;
        float4 v = ((const float4*)h2t)[((size_t)b*L4K + l0 + i)*32 + (c0>>2) + jq];
        int sg = b*32 + (c0>>2) + jq;
        float mn = stats[sg*2], rstd = stats[sg*2+1];
        int c = c0 + jq*4;
        T[(jq*4+0)*33 + i] = (v.x-mn)*rstd*g2[c+0] + b2[c+0];
        T[(jq*4+1)*33 + i] = (v.y-mn)*rstd*g2[c+1] + b2[c+1];
        T[(jq*4+2)*33 + i] = (v.z-mn)*rstd*g2[c+2] + b2[c+2];
        T[(jq*4+3)*33 + i] = (v.w-mn)*rstd*g2[c+3] + b2[c+3];
    }
    __syncthreads();
    {
        int c = tid >> 3, iq = tid & 7;
        size_t gi = ((size_t)b*128 + c0 + c)*1024 + (l0>>2) + iq;
        float4 o = ((const float4*)outp)[gi];
        float4 r;
        r.x = o.x + T[c*33 + iq*4 + 0];
        r.y = o.y + T[c*33 + iq*4 + 1];
        r.z = o.z + T[c*33 + iq*4 + 2];
        r.w = o.w + T[c*33 + iq*4 + 3];
        ((float4*)out)[gi] = r;
    }
}

extern "C" void kernel_launch(void* const* d_in, const int* in_sizes, int n_in,
                              void* d_out, int out_size, void* d_ws, size_t ws_size,
                              hipStream_t stream) {
    (void)in_sizes; (void)n_in; (void)out_size; (void)ws_size;
    const float* x    = (const float*)d_in[0];
    const float* png  = (const float*)d_in[1];
    const float* pnb  = (const float*)d_in[2];
    const float* biw  = (const float*)d_in[3];
    const float* bib  = (const float*)d_in[4];
    const float* ipw  = (const float*)d_in[5];
    const float* cw   = (const float*)d_in[6];
    const float* cb   = (const float*)d_in[7];
    const float* xpw  = (const float*)d_in[8];
    const float* dtw  = (const float*)d_in[9];
    const float* dtb  = (const float*)d_in[10];
    const float* alog = (const float*)d_in[11];
    const float* Dp   = (const float*)d_in[12];
    const float* opw  = (const float*)d_in[13];
    const float* pog  = (const float*)d_in[14];
    const float* pob  = (const float*)d_in[15];
    const float* bow  = (const float*)d_in[16];
    const float* bob  = (const float*)d_in[17];
    const float* rsp  = (const float*)d_in[18];
    const float* f1w  = (const float*)d_in[19];
    const float* g1g  = (const float*)d_in[20];
    const float* g1b  = (const float*)d_in[21];
    const float* f2w  = (const float*)d_in[22];
    const float* g2g  = (const float*)d_in[23];
    const float* g2b  = (const float*)d_in[24];

    char* ws = (char*)d_ws;
    // Phase 1 (mamba), peak 112 MiB. All [n][feature][4096] planes.
    float* S    = (float*)(ws + 0);            // 64 MB, dead after k5
    float* zc   = (float*)(ws + 67108864);     // 8 MB,  dead after k5
    float* zg   = (float*)(ws + 75497472);     // 16 MB, dead after k5
    float* xcp  = (float*)(ws + 92274688);     // 16 MB, dead after k2
    float* y    = (float*)(ws + 92274688);     // aliases xcp
    float* m    = (float*)(ws + 109051904);    // 8 MB (k5->k6)
    float* chA  = (float*)(ws + 109051904);                // 2 MB (pre-k5)
    float* chH  = (float*)(ws + 109051904 + 2097152);      // 2 MB
    float* hst  = (float*)(ws + 109051904 + 4194304);      // 2 MB
    // Phase 2 (post): all alias dead phase-1 regions
    float*          outp  = (float*)(ws + 0);              // 16 MB fp32 [c][l]
    unsigned short* outpb = (unsigned short*)(ws + 16777216); // 8 MB bf16 [l][c]
    unsigned short* h1tb  = (unsigned short*)(ws + 25165824); // 32 MB bf16 [l][512]
    float*          h2t   = (float*)(ws + 58720256);       // 16 MB fp32 [l][128]
    float*          st1   = (float*)(ws + 75497472);       // 2 KB (zg dead)
    float*          st2   = (float*)(ws + 75501568);

    k1_pre<<<dim3(128,8),256,0,stream>>>(x,png,pnb,biw,bib,ipw,zc,xcp,zg);
    k2_conv<<<dim3(32,32),128,0,stream>>>(xcp,cw,cb,xpw,dtw,dtb,S);
    k3a_local<<<dim3(NCH,32),512,0,stream>>>(S,alog,chA,chH);
    k3b_prefix<<<64,256,0,stream>>>(chA,chH,hst);
    k3c_emit<<<dim3(NCH,32),512,0,stream>>>(S,alog,hst,y);
    k5_out<<<1024,256,0,stream>>>(y,S,zg,zc,Dp,opw,m);
    k6_post<<<dim3(64,8),256,0,stream>>>(m,x,pog,pob,bow,bob,rsp,outp,outpb);
    gemm_mfma<1,128,true><<<dim3(32,4,8),256,0,stream>>>(outpb,f1w,(void*)h1tb,128,512);
    k_gn1stats<<<256,256,0,stream>>>(h1tb,st1);
    k9_gngelu<<<8192,256,0,stream>>>(h1tb,st1,g1g,g1b);
    gemm_mfma<4,64,false><<<dim3(64,1,8),256,0,stream>>>(h1tb,f2w,(void*)h2t,512,128);
    k_gn2stats<<<256,256,0,stream>>>(h2t,st2);
    k12_final<<<dim3(128,4,8),256,0,stream>>>(outp,h2t,st2,g2g,g2b,(float*)d_out);
}